// Round 3
// baseline (250.971 us; speedup 1.0000x reference)
//
#include <hip/hip_runtime.h>

// ChessMultiStageAttention: B=4096 fused blocks of (pos-add, LN, QKV, 8-head
// attention S=64 D=8 with chess bias, out-proj, residual). f32 I/O, bf16 MFMA
// (16x16x32_bf16) with f32 accum. One 256-thread WG per batch item.
//
// MFMA layouts (m89-verified):
//   A: lane m=lane&15 holds row m, k=(lane>>4)*8+j (k-contiguous 16B)
//   B: lane n=lane&15 holds col n, k=(lane>>4)*8+j (stored [n][k], k-contig)
//   C/D: col=lane&15, row=(lane>>4)*4+reg
//
// LDS plan (35840 B -> 4 WG/CU, 16 waves/CU):
//   R1 [64][136] bf16: (A-C) f32 x+pos view [64][68] / (D-E) QK: Q cols 0..63,
//       K cols 64..127 / (E-F) AO overwrites K cols in-place (wave-private:
//       wave w consumes head h's K frags before writing head h's AO there)
//   R2 [64][72]  bf16: (C-D) x_norm / (E) per-wave P tile (rows 16w..16w+15)
//   R3 [64][72]  bf16: (D-E) v^T [(h,d)][t]
// Scores computed TRANSPOSED (S^T = K*Q^T) so P is written as packed b64
// (4 consecutive t per lane) instead of 16 scalar b16 stores per tile.

typedef __attribute__((ext_vector_type(8))) __bf16 bfrag;
typedef __attribute__((ext_vector_type(4))) __bf16 bf4;
typedef __attribute__((ext_vector_type(4))) float f32x4;

#define MFMA16(a, b, c) __builtin_amdgcn_mfma_f32_16x16x32_bf16((a), (b), (c), 0, 0, 0)

static __device__ __forceinline__ bfrag bsplat(float v) {
  bfrag z;
#pragma unroll
  for (int i = 0; i < 8; i++) z[i] = (__bf16)v;
  return z;
}

static __device__ __forceinline__ bfrag cvt8(const float* __restrict__ p) {
  float4 a = *(const float4*)p, b = *(const float4*)(p + 4);
  bfrag r;
  r[0] = (__bf16)a.x; r[1] = (__bf16)a.y; r[2] = (__bf16)a.z; r[3] = (__bf16)a.w;
  r[4] = (__bf16)b.x; r[5] = (__bf16)b.y; r[6] = (__bf16)b.z; r[7] = (__bf16)b.w;
  return r;
}

__global__ __launch_bounds__(256, 4) void chess_attn_kernel(
    const float* __restrict__ xg,    const float* __restrict__ posg,
    const float* __restrict__ gam,   const float* __restrict__ bet,
    const float* __restrict__ qkvw,  const float* __restrict__ qkvb,
    const float* __restrict__ outw,  const float* __restrict__ outb,
    const float* __restrict__ biasg, float* __restrict__ outg) {
  __shared__ __attribute__((aligned(16))) __bf16 R1[64 * 136];  // 17408 B
  __shared__ __attribute__((aligned(16))) __bf16 R2[64 * 72];   //  9216 B
  __shared__ __attribute__((aligned(16))) __bf16 R3[64 * 72];   //  9216 B

  const int tid = threadIdx.x, lane = tid & 63, w = tid >> 6;
  const int m = lane & 15, g = lane >> 4;
  const int b = blockIdx.x;
  const float LN2I = 1.4426950408889634f;            // log2(e)
  const float SCL2 = 0.35355339059327373f * LN2I;    // (1/sqrt(8))*log2(e)
  float* XPREf = (float*)R1;                         // [64][68] f32 view

  // ---- A: x + pos -> XPREf[s][e]; wave w fills rows 16w..16w+15 entirely ----
  {
    const float4* px = (const float4*)(xg + ((size_t)b * 64 + lane) * 64 + w * 16);
    const float4* pp = (const float4*)(posg + (size_t)lane * 64 + w * 16);
#pragma unroll
    for (int v = 0; v < 4; v++) {
      float4 xv = px[v], pv = pp[v];
      const int s = w * 16 + v * 4;
      XPREf[(s + 0) * 68 + lane] = xv.x + pv.x;
      XPREf[(s + 1) * 68 + lane] = xv.y + pv.y;
      XPREf[(s + 2) * 68 + lane] = xv.z + pv.z;
      XPREf[(s + 3) * 68 + lane] = xv.w + pv.w;
    }
  }
  // no barrier: stage B thread reads row tid>>2, written by wave (tid>>2)>>4 == own wave

  // ---- B+C: LayerNorm (4 threads/row, quad shuffle) -> XN in R2 ----
  {
    const int s = tid >> 2, q = tid & 3;
    const float4* pr = (const float4*)&XPREf[s * 68 + q * 16];
    float4 x0 = pr[0], x1 = pr[1], x2 = pr[2], x3 = pr[3];
    float xr[16] = {x0.x, x0.y, x0.z, x0.w, x1.x, x1.y, x1.z, x1.w,
                    x2.x, x2.y, x2.z, x2.w, x3.x, x3.y, x3.z, x3.w};
    float sum = 0.f, ss = 0.f;
#pragma unroll
    for (int i = 0; i < 16; i++) { sum += xr[i]; ss = fmaf(xr[i], xr[i], ss); }
    sum += __shfl_xor(sum, 1); ss += __shfl_xor(ss, 1);
    sum += __shfl_xor(sum, 2); ss += __shfl_xor(ss, 2);
    const float mu = sum * 0.015625f;
    const float rs = __builtin_amdgcn_rsqf(ss * 0.015625f - mu * mu + 1e-5f);
    const float4* pg = (const float4*)(gam + q * 16);
    const float4* pb = (const float4*)(bet + q * 16);
    float4 g0 = pg[0], g1 = pg[1], g2 = pg[2], g3 = pg[3];
    float4 b0 = pb[0], b1 = pb[1], b2 = pb[2], b3 = pb[3];
    float gr[16] = {g0.x, g0.y, g0.z, g0.w, g1.x, g1.y, g1.z, g1.w,
                    g2.x, g2.y, g2.z, g2.w, g3.x, g3.y, g3.z, g3.w};
    float br[16] = {b0.x, b0.y, b0.z, b0.w, b1.x, b1.y, b1.z, b1.w,
                    b2.x, b2.y, b2.z, b2.w, b3.x, b3.y, b3.z, b3.w};
    bfrag o0, o1;
#pragma unroll
    for (int i = 0; i < 8; i++) o0[i] = (__bf16)((xr[i] - mu) * rs * gr[i] + br[i]);
#pragma unroll
    for (int i = 0; i < 8; i++) o1[i] = (__bf16)((xr[8 + i] - mu) * rs * gr[8 + i] + br[8 + i]);
    *(bfrag*)&R2[s * 72 + q * 16] = o0;
    *(bfrag*)&R2[s * 72 + q * 16 + 8] = o1;
  }
  __syncthreads();

  // ---- D: QKV projection; wave w covers n in [48w, 48w+48) ----
  {
    bfrag A0[4], A1[4];
#pragma unroll
    for (int mt = 0; mt < 4; mt++) {
      A0[mt] = *(const bfrag*)&R2[(mt * 16 + m) * 72 + g * 8];
      A1[mt] = *(const bfrag*)&R2[(mt * 16 + m) * 72 + 32 + g * 8];
    }
#pragma unroll
    for (int nt = 0; nt < 3; nt++) {
      const int nb = w * 48 + nt * 16;
      const int n  = nb + m;
      bfrag B0 = cvt8(qkvw + (size_t)n * 64 + g * 8);
      bfrag B1 = cvt8(qkvw + (size_t)n * 64 + 32 + g * 8);
      const float qb = qkvb[n];
#pragma unroll
      for (int mt = 0; mt < 4; mt++) {
        f32x4 c = {0.f, 0.f, 0.f, 0.f};
        c = MFMA16(A0[mt], B0, c);
        c = MFMA16(A1[mt], B1, c);
        if (nb < 128) {                 // q (n<64) or k (64..127) -> R1[s][n]
#pragma unroll
          for (int r = 0; r < 4; r++)
            R1[(mt * 16 + g * 4 + r) * 136 + n] = (__bf16)(c[r] + qb);
        } else {                        // v -> R3[(h,d)][t] packed b64
          bf4 pk;
#pragma unroll
          for (int r = 0; r < 4; r++) pk[r] = (__bf16)(c[r] + qb);
          *(bf4*)&R3[(n - 128) * 72 + mt * 16 + g * 4] = pk;
        }
      }
    }
  }
  __syncthreads();

  // ---- E: attention, heads h = w, w+4; scores transposed ----
  const bfrag ZF  = bsplat(0.f);
  const bfrag ONE = bsplat(1.f);
  __bf16* Pw = &R2[(w * 16) * 72];     // per-wave P tile [16][72]
#pragma unroll 1
  for (int hl = 0; hl < 2; hl++) {
    const int h = w + hl * 4;
    bfrag KA[4];                        // A = K rows t (this wave's head only)
#pragma unroll
    for (int tt = 0; tt < 4; tt++)
      KA[tt] = (lane < 16) ? *(const bfrag*)&R1[(tt * 16 + m) * 136 + 64 + h * 8] : ZF;
    bfrag VA[2];                        // A = V^T rows d; row 8 = ones (row-sum trick)
#pragma unroll
    for (int kf = 0; kf < 2; kf++)
      VA[kf] = (m < 8) ? *(const bfrag*)&R3[(h * 8 + m) * 72 + kf * 32 + g * 8]
                       : ((m == 8) ? ONE : ZF);
#pragma unroll 1
    for (int st = 0; st < 4; st++) {
      bfrag QB = (lane < 16) ? *(const bfrag*)&R1[(st * 16 + m) * 136 + h * 8] : ZF;
      f32x4 sc4[4];
#pragma unroll
      for (int tt = 0; tt < 4; tt++) {
        f32x4 c = {0.f, 0.f, 0.f, 0.f};
        sc4[tt] = MFMA16(KA[tt], QB, c);   // C: col=s, rows=t (4 consecutive)
      }
#pragma unroll
      for (int tt = 0; tt < 4; tt++) {
        float4 bv = *(const float4*)(biasg + (size_t)(st * 16 + m) * 64 + tt * 16 + g * 4);
        bf4 pk;
        pk[0] = (__bf16)__builtin_amdgcn_exp2f(fmaf(bv.x, LN2I, sc4[tt][0] * SCL2));
        pk[1] = (__bf16)__builtin_amdgcn_exp2f(fmaf(bv.y, LN2I, sc4[tt][1] * SCL2));
        pk[2] = (__bf16)__builtin_amdgcn_exp2f(fmaf(bv.z, LN2I, sc4[tt][2] * SCL2));
        pk[3] = (__bf16)__builtin_amdgcn_exp2f(fmaf(bv.w, LN2I, sc4[tt][3] * SCL2));
        *(bf4*)&Pw[m * 72 + tt * 16 + g * 4] = pk;   // P[s][t], one b64 per tile
      }
      __threadfence_block();            // P writes -> B-frag reads (same wave)
      bfrag PB0 = *(const bfrag*)&Pw[m * 72 + g * 8];
      bfrag PB1 = *(const bfrag*)&Pw[m * 72 + 32 + g * 8];
      f32x4 oo = {0.f, 0.f, 0.f, 0.f};
      oo = MFMA16(VA[0], PB0, oo);      // O^T: col=s, rows=d; row 8 = row-sum
      oo = MFMA16(VA[1], PB1, oo);
      const float rsum = __builtin_amdgcn_rcpf(__shfl(oo[0], 32 + m));
      bf4 ov;
#pragma unroll
      for (int r = 0; r < 4; r++) ov[r] = (__bf16)(oo[r] * rsum);
      // AO[s][h*8+d] overwrites this head's (already-consumed) K columns
      if (g < 2) *(bf4*)&R1[(st * 16 + m) * 136 + 64 + h * 8 + g * 4] = ov;
    }
  }
  __syncthreads();

  // ---- F: out-proj OP[e][s] = out_w * AO^T + residual (re-read x+pos) ----
  {
    const int sc_ = w * 16 + m;         // this wave's 16 output positions
    bfrag BO0 = *(const bfrag*)&R1[sc_ * 136 + 64 + g * 8];
    bfrag BO1 = *(const bfrag*)&R1[sc_ * 136 + 96 + g * 8];
    const size_t xoff = (size_t)b * 4096;
#pragma unroll
    for (int mt = 0; mt < 4; mt++) {
      bfrag AW0 = cvt8(outw + (size_t)(mt * 16 + m) * 64 + g * 8);
      bfrag AW1 = cvt8(outw + (size_t)(mt * 16 + m) * 64 + 32 + g * 8);
      f32x4 c = {0.f, 0.f, 0.f, 0.f};
      c = MFMA16(AW0, BO0, c);
      c = MFMA16(AW1, BO1, c);
#pragma unroll
      for (int r = 0; r < 4; r++) {
        const int e = mt * 16 + g * 4 + r;
        outg[xoff + (size_t)e * 64 + sc_] =
            c[r] + outb[e] + xg[xoff + (size_t)e * 64 + sc_] + posg[(size_t)e * 64 + sc_];
      }
    }
  }
}

extern "C" void kernel_launch(void* const* d_in, const int* in_sizes, int n_in,
                              void* d_out, int out_size, void* d_ws, size_t ws_size,
                              hipStream_t stream) {
  const float* xg   = (const float*)d_in[0];
  const float* pos  = (const float*)d_in[1];
  const float* gam  = (const float*)d_in[2];
  const float* bet  = (const float*)d_in[3];
  const float* qkvw = (const float*)d_in[4];
  const float* qkvb = (const float*)d_in[5];
  const float* outw = (const float*)d_in[6];
  const float* outb = (const float*)d_in[7];
  const float* cb   = (const float*)d_in[8];
  float* out = (float*)d_out;
  const int B = in_sizes[0] / (64 * 64);   // 4096
  hipLaunchKernelGGL(chess_attn_kernel, dim3(B), dim3(256), 0, stream,
                     xg, pos, gam, bet, qkvw, qkvb, outw, outb, cb, out);
}

// Round 4
// 233.225 us; speedup vs baseline: 1.0761x; 1.0761x over previous
//
#include <hip/hip_runtime.h>
#include <stdint.h>

// ChessMultiStageAttention: B=4096 fused blocks of (pos-add, LN, QKV, 8-head
// attention S=64 D=8 with chess bias, out-proj, residual). f32 I/O, bf16 MFMA
// (16x16x32_bf16) with f32 accum. One 256-thread WG per batch item.
//
// MFMA layouts (m89-verified):
//   A: lane m=lane&15 holds row m, k=(lane>>4)*8+j (k-contiguous 16B)
//   B: lane n=lane&15 holds col n, k=(lane>>4)*8+j
//   C/D: col=lane&15, row=(lane>>4)*4+reg
//
// Round-4 changes (attack the per-block latency chain):
//  - attention P matrix transposed IN REGISTERS (16 shfl + 8 select) -> no P
//    LDS, no fence, st-loop fully unrolled into 4 independent chains
//  - Q/K computed transposed (A=W,B=XN) -> packed b64 LDS writes
//  - out-proj computed as O[s][e] (A=AO,B=W) -> float4 residual loads/stores
//
// LDS plan (35840 B -> 4 WG/CU):
//   R1 [64][136] bf16: (A-C) f32 x+pos view [64][68] / (D-) Q cols 0..63,
//       K cols 64..127 / (E) AO overwrites own head's K cols (wave-private)
//   R2 [64][72]  bf16: x_norm (C-D)
//   R3 [64][72]  bf16: v^T [(h,d)][t] (D-E)

typedef __attribute__((ext_vector_type(8))) __bf16 bfrag;
typedef __attribute__((ext_vector_type(4))) __bf16 bf4;
typedef __attribute__((ext_vector_type(4))) float f32x4;
typedef __attribute__((ext_vector_type(4))) uint32_t u32x4;

#define MFMA16(a, b, c) __builtin_amdgcn_mfma_f32_16x16x32_bf16((a), (b), (c), 0, 0, 0)

static __device__ __forceinline__ bfrag bsplat(float v) {
  bfrag z;
#pragma unroll
  for (int i = 0; i < 8; i++) z[i] = (__bf16)v;
  return z;
}

static __device__ __forceinline__ bfrag cvt8(const float* __restrict__ p) {
  float4 a = *(const float4*)p, b = *(const float4*)(p + 4);
  bfrag r;
  r[0] = (__bf16)a.x; r[1] = (__bf16)a.y; r[2] = (__bf16)a.z; r[3] = (__bf16)a.w;
  r[4] = (__bf16)b.x; r[5] = (__bf16)b.y; r[6] = (__bf16)b.z; r[7] = (__bf16)b.w;
  return r;
}

static __device__ __forceinline__ uint32_t pack2(float a, float b) {
  unsigned short ua = __builtin_bit_cast(unsigned short, (__bf16)a);
  unsigned short ub = __builtin_bit_cast(unsigned short, (__bf16)b);
  return (uint32_t)ua | ((uint32_t)ub << 16);
}

__global__ __launch_bounds__(256, 4) void chess_attn_kernel(
    const float* __restrict__ xg,    const float* __restrict__ posg,
    const float* __restrict__ gam,   const float* __restrict__ bet,
    const float* __restrict__ qkvw,  const float* __restrict__ qkvb,
    const float* __restrict__ outw,  const float* __restrict__ outb,
    const float* __restrict__ biasg, float* __restrict__ outg) {
  __shared__ __attribute__((aligned(16))) __bf16 R1[64 * 136];  // 17408 B
  __shared__ __attribute__((aligned(16))) __bf16 R2[64 * 72];   //  9216 B
  __shared__ __attribute__((aligned(16))) __bf16 R3[64 * 72];   //  9216 B

  const int tid = threadIdx.x, lane = tid & 63, w = tid >> 6;
  const int m = lane & 15, g = lane >> 4;
  const int b = blockIdx.x;
  const float LN2I = 1.4426950408889634f;            // log2(e)
  const float SCL2 = 0.35355339059327373f * LN2I;    // (1/sqrt(8))*log2(e)
  float* XPREf = (float*)R1;                         // [64][68] f32 view

  // ---- A: x + pos -> XPREf[s][e]; wave w fills rows 16w..16w+15 ----
  {
    const float4* px = (const float4*)(xg + ((size_t)b * 64 + lane) * 64 + w * 16);
    const float4* pp = (const float4*)(posg + (size_t)lane * 64 + w * 16);
#pragma unroll
    for (int v = 0; v < 4; v++) {
      float4 xv = px[v], pv = pp[v];
      const int s = w * 16 + v * 4;
      XPREf[(s + 0) * 68 + lane] = xv.x + pv.x;
      XPREf[(s + 1) * 68 + lane] = xv.y + pv.y;
      XPREf[(s + 2) * 68 + lane] = xv.z + pv.z;
      XPREf[(s + 3) * 68 + lane] = xv.w + pv.w;
    }
  }
  // no barrier: stage B thread reads row tid>>2 written by its own wave

  // ---- B+C: LayerNorm (4 threads/row, quad shuffle) -> XN in R2 ----
  {
    const int s = tid >> 2, q = tid & 3;
    const float4* pr = (const float4*)&XPREf[s * 68 + q * 16];
    float4 x0 = pr[0], x1 = pr[1], x2 = pr[2], x3 = pr[3];
    float xr[16] = {x0.x, x0.y, x0.z, x0.w, x1.x, x1.y, x1.z, x1.w,
                    x2.x, x2.y, x2.z, x2.w, x3.x, x3.y, x3.z, x3.w};
    float sum = 0.f, ss = 0.f;
#pragma unroll
    for (int i = 0; i < 16; i++) { sum += xr[i]; ss = fmaf(xr[i], xr[i], ss); }
    sum += __shfl_xor(sum, 1); ss += __shfl_xor(ss, 1);
    sum += __shfl_xor(sum, 2); ss += __shfl_xor(ss, 2);
    const float mu = sum * 0.015625f;
    const float rs = __builtin_amdgcn_rsqf(ss * 0.015625f - mu * mu + 1e-5f);
    const float4* pg = (const float4*)(gam + q * 16);
    const float4* pb = (const float4*)(bet + q * 16);
    float4 g0 = pg[0], g1 = pg[1], g2 = pg[2], g3 = pg[3];
    float4 b0 = pb[0], b1 = pb[1], b2 = pb[2], b3 = pb[3];
    float gr[16] = {g0.x, g0.y, g0.z, g0.w, g1.x, g1.y, g1.z, g1.w,
                    g2.x, g2.y, g2.z, g2.w, g3.x, g3.y, g3.z, g3.w};
    float br[16] = {b0.x, b0.y, b0.z, b0.w, b1.x, b1.y, b1.z, b1.w,
                    b2.x, b2.y, b2.z, b2.w, b3.x, b3.y, b3.z, b3.w};
    bfrag o0, o1;
#pragma unroll
    for (int i = 0; i < 8; i++) o0[i] = (__bf16)((xr[i] - mu) * rs * gr[i] + br[i]);
#pragma unroll
    for (int i = 0; i < 8; i++) o1[i] = (__bf16)((xr[8 + i] - mu) * rs * gr[8 + i] + br[8 + i]);
    *(bfrag*)&R2[s * 72 + q * 16] = o0;
    *(bfrag*)&R2[s * 72 + q * 16 + 8] = o1;
  }
  __syncthreads();

  // ---- D: QKV. XN frags serve as B (for Q/K transposed) and A (for V) ----
  {
    bfrag XF[4][2];
#pragma unroll
    for (int st = 0; st < 4; st++) {
      XF[st][0] = *(const bfrag*)&R2[(st * 16 + m) * 72 + g * 8];
      XF[st][1] = *(const bfrag*)&R2[(st * 16 + m) * 72 + 32 + g * 8];
    }
    // Q and K tiles, transposed (A=W rows n, B=XN): wave w -> n-tiles w, w+4
#pragma unroll
    for (int i = 0; i < 2; i++) {
      const int nt = w + 4 * i;                       // n-tile 0..7 (Q:0-3, K:4-7)
      bfrag AW0 = cvt8(qkvw + (size_t)(nt * 16 + m) * 64 + g * 8);
      bfrag AW1 = cvt8(qkvw + (size_t)(nt * 16 + m) * 64 + 32 + g * 8);
      float4 qb4 = *(const float4*)(qkvb + nt * 16 + g * 4);
#pragma unroll
      for (int st = 0; st < 4; st++) {
        f32x4 c = {0.f, 0.f, 0.f, 0.f};
        c = MFMA16(AW0, XF[st][0], c);                // C: col=s, rows=n (4 consec)
        c = MFMA16(AW1, XF[st][1], c);
        bf4 pk;
        pk[0] = (__bf16)(c[0] + qb4.x); pk[1] = (__bf16)(c[1] + qb4.y);
        pk[2] = (__bf16)(c[2] + qb4.z); pk[3] = (__bf16)(c[3] + qb4.w);
        *(bf4*)&R1[(st * 16 + m) * 136 + nt * 16 + g * 4] = pk;
      }
    }
    // V tile (normal orientation: A=XN rows s, B=W cols n): wave w -> v rows 16w..
    {
      const int n = 128 + w * 16 + m;
      bfrag BV0 = cvt8(qkvw + (size_t)n * 64 + g * 8);
      bfrag BV1 = cvt8(qkvw + (size_t)n * 64 + 32 + g * 8);
      const float vb = qkvb[n];
#pragma unroll
      for (int st = 0; st < 4; st++) {
        f32x4 c = {0.f, 0.f, 0.f, 0.f};
        c = MFMA16(XF[st][0], BV0, c);                // C: col=v-row, rows=s (4 consec)
        c = MFMA16(XF[st][1], BV1, c);
        bf4 pk;
#pragma unroll
        for (int r = 0; r < 4; r++) pk[r] = (__bf16)(c[r] + vb);
        *(bf4*)&R3[(w * 16 + m) * 72 + st * 16 + g * 4] = pk;
      }
    }
  }
  __syncthreads();

  // ---- E: attention, heads h = w, w+4; S^T = K*Q^T; P transposed in-register ----
  const bfrag ZF  = bsplat(0.f);
  const bfrag ONE = bsplat(1.f);
#pragma unroll 1
  for (int hl = 0; hl < 2; hl++) {
    const int h = w + hl * 4;
    bfrag KA[4];                        // A = K rows t (own head only)
#pragma unroll
    for (int tt = 0; tt < 4; tt++)
      KA[tt] = (lane < 16) ? *(const bfrag*)&R1[(tt * 16 + m) * 136 + 64 + h * 8] : ZF;
    bfrag VA[2];                        // A = V^T rows d; row 8 = ones (row-sum)
#pragma unroll
    for (int kf = 0; kf < 2; kf++)
      VA[kf] = (m < 8) ? *(const bfrag*)&R3[(h * 8 + m) * 72 + kf * 32 + g * 8]
                       : ((m == 8) ? ONE : ZF);
    const int srcA = m + 32 * (g & 1);  // P-transpose source lanes
    const int srcB = srcA + 16;
    const bool hi = (g >= 2);
#pragma unroll
    for (int st = 0; st < 4; st++) {
      bfrag QB = (lane < 16) ? *(const bfrag*)&R1[(st * 16 + m) * 136 + h * 8] : ZF;
      f32x4 sc[4];
#pragma unroll
      for (int tt = 0; tt < 4; tt++) {
        f32x4 z = {0.f, 0.f, 0.f, 0.f};
        sc[tt] = MFMA16(KA[tt], QB, z);   // col=s, rows=t (4 consecutive per lane)
      }
      uint32_t pk[4][2];                  // exp, packed to bf16 pairs (t, t+1)
#pragma unroll
      for (int tt = 0; tt < 4; tt++) {
        float4 bv = *(const float4*)(biasg + (size_t)(st * 16 + m) * 64 + tt * 16 + g * 4);
        float e0 = __builtin_amdgcn_exp2f(fmaf(bv.x, LN2I, sc[tt][0] * SCL2));
        float e1 = __builtin_amdgcn_exp2f(fmaf(bv.y, LN2I, sc[tt][1] * SCL2));
        float e2 = __builtin_amdgcn_exp2f(fmaf(bv.z, LN2I, sc[tt][2] * SCL2));
        float e3 = __builtin_amdgcn_exp2f(fmaf(bv.w, LN2I, sc[tt][3] * SCL2));
        pk[tt][0] = pack2(e0, e1);
        pk[tt][1] = pack2(e2, e3);
      }
      // In-register transpose: build PV B-frags (lane s holds 8 consecutive t)
      u32x4 U0, U1;
      {
        uint32_t a0 = __shfl((int)pk[0][0], srcA), a1 = __shfl((int)pk[1][0], srcA);
        uint32_t b0 = __shfl((int)pk[0][1], srcA), b1 = __shfl((int)pk[1][1], srcA);
        uint32_t c0 = __shfl((int)pk[0][0], srcB), c1 = __shfl((int)pk[1][0], srcB);
        uint32_t d0 = __shfl((int)pk[0][1], srcB), d1 = __shfl((int)pk[1][1], srcB);
        U0[0] = hi ? a1 : a0; U0[1] = hi ? b1 : b0;
        U0[2] = hi ? c1 : c0; U0[3] = hi ? d1 : d0;
      }
      {
        uint32_t a0 = __shfl((int)pk[2][0], srcA), a1 = __shfl((int)pk[3][0], srcA);
        uint32_t b0 = __shfl((int)pk[2][1], srcA), b1 = __shfl((int)pk[3][1], srcA);
        uint32_t c0 = __shfl((int)pk[2][0], srcB), c1 = __shfl((int)pk[3][0], srcB);
        uint32_t d0 = __shfl((int)pk[2][1], srcB), d1 = __shfl((int)pk[3][1], srcB);
        U1[0] = hi ? a1 : a0; U1[1] = hi ? b1 : b0;
        U1[2] = hi ? c1 : c0; U1[3] = hi ? d1 : d0;
      }
      bfrag PB0 = __builtin_bit_cast(bfrag, U0);
      bfrag PB1 = __builtin_bit_cast(bfrag, U1);
      f32x4 oo = {0.f, 0.f, 0.f, 0.f};
      oo = MFMA16(VA[0], PB0, oo);        // O^T: col=s, rows=d; row 8 = row-sum
      oo = MFMA16(VA[1], PB1, oo);
      const float rsum = __builtin_amdgcn_rcpf(__shfl(oo[0], 32 + m));
      bf4 ov;
#pragma unroll
      for (int r = 0; r < 4; r++) ov[r] = (__bf16)(oo[r] * rsum);
      // AO[s][h*8+d] overwrites this head's (already-consumed) K columns
      if (g < 2) *(bf4*)&R1[(st * 16 + m) * 136 + 64 + h * 8 + g * 4] = ov;
    }
  }
  __syncthreads();

  // ---- F: O[s][e] = AO * out_w^T (A=AO rows s, B=W rows e) + residual ----
  {
    bfrag A0 = *(const bfrag*)&R1[(w * 16 + m) * 136 + 64 + g * 8];
    bfrag A1 = *(const bfrag*)&R1[(w * 16 + m) * 136 + 96 + g * 8];
    const int sbase = w * 16 + g * 4;
    const size_t xoff = (size_t)b * 4096;
#pragma unroll
    for (int et = 0; et < 4; et++) {
      const int e = et * 16 + m;
      bfrag BW0 = cvt8(outw + (size_t)e * 64 + g * 8);
      bfrag BW1 = cvt8(outw + (size_t)e * 64 + 32 + g * 8);
      f32x4 c = {0.f, 0.f, 0.f, 0.f};
      c = MFMA16(A0, BW0, c);             // col=e, rows=s (4 consecutive per lane)
      c = MFMA16(A1, BW1, c);
      const float ob = outb[e];
      float4 xv = *(const float4*)(xg + xoff + (size_t)e * 64 + sbase);
      float4 pv = *(const float4*)(posg + (size_t)e * 64 + sbase);
      float4 o;
      o.x = c[0] + ob + xv.x + pv.x;
      o.y = c[1] + ob + xv.y + pv.y;
      o.z = c[2] + ob + xv.z + pv.z;
      o.w = c[3] + ob + xv.w + pv.w;
      *(float4*)(outg + xoff + (size_t)e * 64 + sbase) = o;
    }
  }
}

extern "C" void kernel_launch(void* const* d_in, const int* in_sizes, int n_in,
                              void* d_out, int out_size, void* d_ws, size_t ws_size,
                              hipStream_t stream) {
  const float* xg   = (const float*)d_in[0];
  const float* pos  = (const float*)d_in[1];
  const float* gam  = (const float*)d_in[2];
  const float* bet  = (const float*)d_in[3];
  const float* qkvw = (const float*)d_in[4];
  const float* qkvb = (const float*)d_in[5];
  const float* outw = (const float*)d_in[6];
  const float* outb = (const float*)d_in[7];
  const float* cb   = (const float*)d_in[8];
  float* out = (float*)d_out;
  const int B = in_sizes[0] / (64 * 64);   // 4096
  hipLaunchKernelGGL(chess_attn_kernel, dim3(B), dim3(256), 0, stream,
                     xg, pos, gam, bet, qkvw, qkvb, outw, outb, cb, out);
}

// Round 5
// 192.969 us; speedup vs baseline: 1.3006x; 1.2086x over previous
//
#include <hip/hip_runtime.h>
#include <stdint.h>

// ChessMultiStageAttention: B=4096 fused blocks of (pos-add, LN, QKV, 8-head
// attention S=64 D=8 with chess bias, out-proj, residual). f32 I/O, bf16 MFMA
// (16x16x32_bf16) with f32 accum.
//
// Round-5: TWO batch items per 256-thread WG; every wave executes both items'
// work in each stage (2 independent dep-chains per wave = 2x ILP), weight /
// bias / gamma-beta / pos loads shared across items, barriers per item halved.
//
// MFMA layouts (m89-verified):
//   A: lane m=lane&15 holds row m, k=(lane>>4)*8+j (k-contiguous 16B)
//   B: lane holds col n=lane&15, k=(lane>>4)*8+j
//   C/D: col=lane&15, row=(lane>>4)*4+reg
//
// LDS per item (26624 B; x2 = 53248 B -> 3 WG/CU):
//   P1 [64][136] bf16: (A-B) f32 x+pos view [64][68] / (D) Q cols 0..63,
//       K cols 64..127 / (E) AO overwrites own head's K cols (wave-private)
//   P2 [64][72]  bf16: (C) x_norm -> XF regs / (D-E) v^T [(h,d)][t]

typedef __attribute__((ext_vector_type(8))) __bf16 bfrag;
typedef __attribute__((ext_vector_type(4))) __bf16 bf4;
typedef __attribute__((ext_vector_type(4))) float f32x4;
typedef __attribute__((ext_vector_type(4))) uint32_t u32x4;

#define MFMA16(a, b, c) __builtin_amdgcn_mfma_f32_16x16x32_bf16((a), (b), (c), 0, 0, 0)

static __device__ __forceinline__ bfrag bsplat(float v) {
  bfrag z;
#pragma unroll
  for (int i = 0; i < 8; i++) z[i] = (__bf16)v;
  return z;
}

static __device__ __forceinline__ bfrag cvt8(const float* __restrict__ p) {
  float4 a = *(const float4*)p, b = *(const float4*)(p + 4);
  bfrag r;
  r[0] = (__bf16)a.x; r[1] = (__bf16)a.y; r[2] = (__bf16)a.z; r[3] = (__bf16)a.w;
  r[4] = (__bf16)b.x; r[5] = (__bf16)b.y; r[6] = (__bf16)b.z; r[7] = (__bf16)b.w;
  return r;
}

static __device__ __forceinline__ uint32_t pack2(float a, float b) {
  unsigned short ua = __builtin_bit_cast(unsigned short, (__bf16)a);
  unsigned short ub = __builtin_bit_cast(unsigned short, (__bf16)b);
  return (uint32_t)ua | ((uint32_t)ub << 16);
}

__global__ __launch_bounds__(256, 3) void chess_attn_kernel(
    const float* __restrict__ xg,    const float* __restrict__ posg,
    const float* __restrict__ gam,   const float* __restrict__ bet,
    const float* __restrict__ qkvw,  const float* __restrict__ qkvb,
    const float* __restrict__ outw,  const float* __restrict__ outb,
    const float* __restrict__ biasg, float* __restrict__ outg) {
  __shared__ __attribute__((aligned(16))) __bf16 P1[2][64 * 136];  // 2x17408 B
  __shared__ __attribute__((aligned(16))) __bf16 P2[2][64 * 72];   // 2x 9216 B

  const int tid = threadIdx.x, lane = tid & 63, w = tid >> 6;
  const int m = lane & 15, g = lane >> 4;
  const int b0 = blockIdx.x * 2;
  const float LN2I = 1.4426950408889634f;            // log2(e)
  const float SCL2 = 0.35355339059327373f * LN2I;    // (1/sqrt(8))*log2(e)

  // ---- A: x + pos -> P1[it] as f32 [64][68]; wave w fills rows 16w..16w+15 ----
  {
    const float4* pp = (const float4*)(posg + (size_t)lane * 64 + w * 16);
    float4 pv[4] = {pp[0], pp[1], pp[2], pp[3]};     // shared across items
#pragma unroll
    for (int it = 0; it < 2; it++) {
      float* XP = (float*)P1[it];
      const float4* px = (const float4*)(xg + ((size_t)(b0 + it) * 64 + lane) * 64 + w * 16);
#pragma unroll
      for (int v = 0; v < 4; v++) {
        float4 xv = px[v];
        const int s = w * 16 + v * 4;
        XP[(s + 0) * 68 + lane] = xv.x + pv[v].x;
        XP[(s + 1) * 68 + lane] = xv.y + pv[v].y;
        XP[(s + 2) * 68 + lane] = xv.z + pv[v].z;
        XP[(s + 3) * 68 + lane] = xv.w + pv[v].w;
      }
    }
  }
  // no barrier: stage B thread reads row tid>>2, written by its own wave

  // ---- B+C: LayerNorm (4 threads/row, quad shuffle) -> XN in P2[it] ----
  {
    const int s = tid >> 2, q = tid & 3;
    const float4* pg = (const float4*)(gam + q * 16);
    const float4* pb = (const float4*)(bet + q * 16);
    float4 g0 = pg[0], g1 = pg[1], g2 = pg[2], g3 = pg[3];
    float4 b0v = pb[0], b1 = pb[1], b2 = pb[2], b3 = pb[3];
    float gr[16] = {g0.x, g0.y, g0.z, g0.w, g1.x, g1.y, g1.z, g1.w,
                    g2.x, g2.y, g2.z, g2.w, g3.x, g3.y, g3.z, g3.w};
    float br[16] = {b0v.x, b0v.y, b0v.z, b0v.w, b1.x, b1.y, b1.z, b1.w,
                    b2.x, b2.y, b2.z, b2.w, b3.x, b3.y, b3.z, b3.w};
#pragma unroll
    for (int it = 0; it < 2; it++) {
      const float* XP = (const float*)P1[it];
      const float4* pr = (const float4*)&XP[s * 68 + q * 16];
      float4 x0 = pr[0], x1 = pr[1], x2 = pr[2], x3 = pr[3];
      float xr[16] = {x0.x, x0.y, x0.z, x0.w, x1.x, x1.y, x1.z, x1.w,
                      x2.x, x2.y, x2.z, x2.w, x3.x, x3.y, x3.z, x3.w};
      float sum = 0.f, ss = 0.f;
#pragma unroll
      for (int i = 0; i < 16; i++) { sum += xr[i]; ss = fmaf(xr[i], xr[i], ss); }
      sum += __shfl_xor(sum, 1); ss += __shfl_xor(ss, 1);
      sum += __shfl_xor(sum, 2); ss += __shfl_xor(ss, 2);
      const float mu = sum * 0.015625f;
      const float rs = __builtin_amdgcn_rsqf(ss * 0.015625f - mu * mu + 1e-5f);
      bfrag o0, o1;
#pragma unroll
      for (int i = 0; i < 8; i++) o0[i] = (__bf16)((xr[i] - mu) * rs * gr[i] + br[i]);
#pragma unroll
      for (int i = 0; i < 8; i++) o1[i] = (__bf16)((xr[8 + i] - mu) * rs * gr[8 + i] + br[8 + i]);
      *(bfrag*)&P2[it][s * 72 + q * 16] = o0;
      *(bfrag*)&P2[it][s * 72 + q * 16 + 8] = o1;
    }
  }
  __syncthreads();   // #1: XN visible to all waves

  // ---- D: QKV. XF frags (both items) then Q/K/V with shared weight loads ----
  bfrag XF[2][4][2];
#pragma unroll
  for (int it = 0; it < 2; it++)
#pragma unroll
    for (int st = 0; st < 4; st++) {
      XF[it][st][0] = *(const bfrag*)&P2[it][(st * 16 + m) * 72 + g * 8];
      XF[it][st][1] = *(const bfrag*)&P2[it][(st * 16 + m) * 72 + 32 + g * 8];
    }
  __syncthreads();   // #2: XF loaded everywhere; V may now overwrite P2

  {
    // Q and K tiles, transposed (A=W rows n, B=XN): wave w -> n-tiles w, w+4
#pragma unroll
    for (int i = 0; i < 2; i++) {
      const int nt = w + 4 * i;                       // 0..7 (Q: 0-3, K: 4-7)
      bfrag AW0 = cvt8(qkvw + (size_t)(nt * 16 + m) * 64 + g * 8);
      bfrag AW1 = cvt8(qkvw + (size_t)(nt * 16 + m) * 64 + 32 + g * 8);
      float4 qb4 = *(const float4*)(qkvb + nt * 16 + g * 4);
#pragma unroll
      for (int it = 0; it < 2; it++)
#pragma unroll
        for (int st = 0; st < 4; st++) {
          f32x4 c = {0.f, 0.f, 0.f, 0.f};
          c = MFMA16(AW0, XF[it][st][0], c);          // C: col=s, rows=n
          c = MFMA16(AW1, XF[it][st][1], c);
          bf4 pk;
          pk[0] = (__bf16)(c[0] + qb4.x); pk[1] = (__bf16)(c[1] + qb4.y);
          pk[2] = (__bf16)(c[2] + qb4.z); pk[3] = (__bf16)(c[3] + qb4.w);
          *(bf4*)&P1[it][(st * 16 + m) * 136 + nt * 16 + g * 4] = pk;
        }
    }
    // V (A=XN rows s, B=W cols n): wave w -> v^T rows 16w..16w+15
    {
      const int n = 128 + w * 16 + m;
      bfrag BV0 = cvt8(qkvw + (size_t)n * 64 + g * 8);
      bfrag BV1 = cvt8(qkvw + (size_t)n * 64 + 32 + g * 8);
      const float vb = qkvb[n];
#pragma unroll
      for (int it = 0; it < 2; it++)
#pragma unroll
        for (int st = 0; st < 4; st++) {
          f32x4 c = {0.f, 0.f, 0.f, 0.f};
          c = MFMA16(XF[it][st][0], BV0, c);          // C: col=v-row, rows=s
          c = MFMA16(XF[it][st][1], BV1, c);
          bf4 pk;
#pragma unroll
          for (int r = 0; r < 4; r++) pk[r] = (__bf16)(c[r] + vb);
          *(bf4*)&P2[it][(w * 16 + m) * 72 + st * 16 + g * 4] = pk;
        }
    }
  }
  __syncthreads();   // #3: Q/K/V complete

  // ---- E: attention, heads h = w, w+4; S^T = K*Q^T; P transposed in-register ----
  const bfrag ZF  = bsplat(0.f);
  const bfrag ONE = bsplat(1.f);
  const int srcA = m + 32 * (g & 1);    // P-transpose source lanes
  const int srcB = srcA + 16;
  const bool hi = (g >= 2);
#pragma unroll 1
  for (int hl = 0; hl < 2; hl++) {
    const int h = w + hl * 4;
    bfrag KA[2][4], VA[2][2];
#pragma unroll
    for (int it = 0; it < 2; it++) {
#pragma unroll
      for (int tt = 0; tt < 4; tt++)
        KA[it][tt] = (lane < 16) ? *(const bfrag*)&P1[it][(tt * 16 + m) * 136 + 64 + h * 8] : ZF;
#pragma unroll
      for (int kf = 0; kf < 2; kf++)
        VA[it][kf] = (m < 8) ? *(const bfrag*)&P2[it][(h * 8 + m) * 72 + kf * 32 + g * 8]
                             : ((m == 8) ? ONE : ZF);
    }
#pragma unroll
    for (int st = 0; st < 4; st++) {
      // bias chunk shared across items
      float4 bv[4];
#pragma unroll
      for (int tt = 0; tt < 4; tt++)
        bv[tt] = *(const float4*)(biasg + (size_t)(st * 16 + m) * 64 + tt * 16 + g * 4);
#pragma unroll
      for (int it = 0; it < 2; it++) {
        bfrag QB = (lane < 16) ? *(const bfrag*)&P1[it][(st * 16 + m) * 136 + h * 8] : ZF;
        f32x4 sc[4];
#pragma unroll
        for (int tt = 0; tt < 4; tt++) {
          f32x4 z = {0.f, 0.f, 0.f, 0.f};
          sc[tt] = MFMA16(KA[it][tt], QB, z);   // col=s, rows=t (4 consec/lane)
        }
        uint32_t pk[4][2];
#pragma unroll
        for (int tt = 0; tt < 4; tt++) {
          float e0 = __builtin_amdgcn_exp2f(fmaf(bv[tt].x, LN2I, sc[tt][0] * SCL2));
          float e1 = __builtin_amdgcn_exp2f(fmaf(bv[tt].y, LN2I, sc[tt][1] * SCL2));
          float e2 = __builtin_amdgcn_exp2f(fmaf(bv[tt].z, LN2I, sc[tt][2] * SCL2));
          float e3 = __builtin_amdgcn_exp2f(fmaf(bv[tt].w, LN2I, sc[tt][3] * SCL2));
          pk[tt][0] = pack2(e0, e1);
          pk[tt][1] = pack2(e2, e3);
        }
        // in-register transpose -> PV B-frags (lane s holds 8 consecutive t)
        u32x4 U0, U1;
        {
          uint32_t a0 = __shfl((int)pk[0][0], srcA), a1 = __shfl((int)pk[1][0], srcA);
          uint32_t c0 = __shfl((int)pk[0][1], srcA), c1 = __shfl((int)pk[1][1], srcA);
          uint32_t a2 = __shfl((int)pk[0][0], srcB), a3 = __shfl((int)pk[1][0], srcB);
          uint32_t c2 = __shfl((int)pk[0][1], srcB), c3 = __shfl((int)pk[1][1], srcB);
          U0[0] = hi ? a1 : a0; U0[1] = hi ? c1 : c0;
          U0[2] = hi ? a3 : a2; U0[3] = hi ? c3 : c2;
        }
        {
          uint32_t a0 = __shfl((int)pk[2][0], srcA), a1 = __shfl((int)pk[3][0], srcA);
          uint32_t c0 = __shfl((int)pk[2][1], srcA), c1 = __shfl((int)pk[3][1], srcA);
          uint32_t a2 = __shfl((int)pk[2][0], srcB), a3 = __shfl((int)pk[3][0], srcB);
          uint32_t c2 = __shfl((int)pk[2][1], srcB), c3 = __shfl((int)pk[3][1], srcB);
          U1[0] = hi ? a1 : a0; U1[1] = hi ? c1 : c0;
          U1[2] = hi ? a3 : a2; U1[3] = hi ? c3 : c2;
        }
        bfrag PB0 = __builtin_bit_cast(bfrag, U0);
        bfrag PB1 = __builtin_bit_cast(bfrag, U1);
        f32x4 oo = {0.f, 0.f, 0.f, 0.f};
        oo = MFMA16(VA[it][0], PB0, oo);      // O^T: col=s, rows=d; row 8 = sum
        oo = MFMA16(VA[it][1], PB1, oo);
        const float rsum = __builtin_amdgcn_rcpf(__shfl(oo[0], 32 + m));
        bf4 ov;
#pragma unroll
        for (int r = 0; r < 4; r++) ov[r] = (__bf16)(oo[r] * rsum);
        // AO[s][h*8+d] overwrites this head's (already-consumed) K columns
        if (g < 2) *(bf4*)&P1[it][(st * 16 + m) * 136 + 64 + h * 8 + g * 4] = ov;
      }
    }
  }
  __syncthreads();   // #4: AO complete

  // ---- F: O[s][e] = AO * out_w^T + residual; weight/pos loads shared ----
  {
    bfrag A0[2], A1[2];
#pragma unroll
    for (int it = 0; it < 2; it++) {
      A0[it] = *(const bfrag*)&P1[it][(w * 16 + m) * 136 + 64 + g * 8];
      A1[it] = *(const bfrag*)&P1[it][(w * 16 + m) * 136 + 96 + g * 8];
    }
    const int sbase = w * 16 + g * 4;
#pragma unroll
    for (int et = 0; et < 4; et++) {
      const int e = et * 16 + m;
      bfrag BW0 = cvt8(outw + (size_t)e * 64 + g * 8);
      bfrag BW1 = cvt8(outw + (size_t)e * 64 + 32 + g * 8);
      const float ob = outb[e];
      float4 pv = *(const float4*)(posg + (size_t)e * 64 + sbase);
#pragma unroll
      for (int it = 0; it < 2; it++) {
        const size_t xoff = (size_t)(b0 + it) * 4096;
        f32x4 c = {0.f, 0.f, 0.f, 0.f};
        c = MFMA16(A0[it], BW0, c);           // col=e, rows=s (4 consec/lane)
        c = MFMA16(A1[it], BW1, c);
        float4 xv = *(const float4*)(xg + xoff + (size_t)e * 64 + sbase);
        float4 o;
        o.x = c[0] + ob + xv.x + pv.x;
        o.y = c[1] + ob + xv.y + pv.y;
        o.z = c[2] + ob + xv.z + pv.z;
        o.w = c[3] + ob + xv.w + pv.w;
        *(float4*)(outg + xoff + (size_t)e * 64 + sbase) = o;
      }
    }
  }
}

extern "C" void kernel_launch(void* const* d_in, const int* in_sizes, int n_in,
                              void* d_out, int out_size, void* d_ws, size_t ws_size,
                              hipStream_t stream) {
  const float* xg   = (const float*)d_in[0];
  const float* pos  = (const float*)d_in[1];
  const float* gam  = (const float*)d_in[2];
  const float* bet  = (const float*)d_in[3];
  const float* qkvw = (const float*)d_in[4];
  const float* qkvb = (const float*)d_in[5];
  const float* outw = (const float*)d_in[6];
  const float* outb = (const float*)d_in[7];
  const float* cb   = (const float*)d_in[8];
  float* out = (float*)d_out;
  const int B = in_sizes[0] / (64 * 64);   // 4096
  hipLaunchKernelGGL(chess_attn_kernel, dim3(B / 2), dim3(256), 0, stream,
                     xg, pos, gam, bet, qkvw, qkvb, outw, outb, cb, out);
}